// Round 4
// baseline (782.442 us; speedup 1.0000x reference)
//
#include <hip/hip_runtime.h>
#include <hip/hip_bf16.h>

#define V 49152
#define NNZ 9
#define EPSV 1e-5f
#define SLOPE 0.1f

// One Chebyshev step fused with GEMM accumulation (all fp32).
// D = B*F (row width of z), F = per-batch feature count.
// INIT: t = zc row (k=0), acc = bias + t@W.  else: t = c1*L*zc + c0*zp, acc += t@W.
// zn may alias zp (in-place T_k over T_{k-2}; own-row read-before-write) -> no __restrict__ on zp/zn.
// DUAL: also accumulate with Wd into accd (shares the Chebyshev basis).
template<int D, int F, bool DUAL, bool INIT>
__global__ __launch_bounds__(256) void cheb_step(
    const float* __restrict__ zc, const float* zp, float* zn,
    const float* __restrict__ vals, const int* __restrict__ col,
    const float* __restrict__ W, const float* __restrict__ bias,
    const float* __restrict__ Wd, const float* __restrict__ biasd,
    float* __restrict__ acc, float* accd,
    float c1, float c0)
{
    __shared__ float ts[4][D];
    int wave = threadIdx.x >> 6;
    int lane = threadIdx.x & 63;
    int v = __builtin_amdgcn_readfirstlane((blockIdx.x << 2) + wave);

    if (INIT) {
        ts[wave][lane] = zc[(size_t)v * D + lane];
        if (D == 128) ts[wave][64 + lane] = zc[(size_t)v * D + 64 + lane];
    } else {
        int base = v * NNZ;
        float t0 = 0.f, t1 = 0.f;
        #pragma unroll
        for (int n = 0; n < NNZ; ++n) {
            float a = vals[base + n];
            int cc = col[base + n];
            cc = cc < 0 ? 0 : (cc >= V ? V - 1 : cc);   // safety clamp (no-op on sane input)
            t0 += a * zc[(size_t)cc * D + lane];
            if (D == 128) t1 += a * zc[(size_t)cc * D + 64 + lane];
        }
        // read zp BEFORE writing zn (same address when in-place)
        float p0 = zp[(size_t)v * D + lane];
        float p1 = (D == 128) ? zp[(size_t)v * D + 64 + lane] : 0.f;
        float r0 = c1 * t0 + c0 * p0;
        zn[(size_t)v * D + lane] = r0;
        ts[wave][lane] = r0;
        if (D == 128) {
            float r1 = c1 * t1 + c0 * p1;
            zn[(size_t)v * D + 64 + lane] = r1;
            ts[wave][64 + lane] = r1;
        }
    }
    __syncthreads();

    int o = lane;
    float a0 = 0.f, a1 = 0.f, d0 = 0.f, d1 = 0.f;
    if (INIT) {
        float bb = bias[o]; a0 = bb; a1 = bb;
        if (DUAL) { float bd = biasd[o]; d0 = bd; d1 = bd; }
    }
    #pragma unroll
    for (int f = 0; f < F; ++f) {
        float w = W[f * 64 + o];
        float t0 = ts[wave][f];
        float t1 = ts[wave][F + f];
        a0 += t0 * w; a1 += t1 * w;
        if (DUAL) {
            float wd = Wd[f * 64 + o];
            d0 += t0 * wd; d1 += t1 * wd;
        }
    }
    size_t i0 = (size_t)v * 64 + o;
    size_t i1 = ((size_t)V + v) * 64 + o;
    if (INIT) {
        acc[i0] = a0; acc[i1] = a1;
        if (DUAL) { accd[i0] = d0; accd[i1] = d1; }
    } else {
        acc[i0] += a0; acc[i1] += a1;
        if (DUAL) { accd[i0] += d0; accd[i1] += d1; }
    }
}

// z0[v*64 + b*32 + f] = x[b][v][f]  (layout shuffle for conv1)
__global__ __launch_bounds__(256) void reorder_k(const float* __restrict__ x, float* __restrict__ z0) {
    int idx = blockIdx.x * 256 + threadIdx.x;   // < V*64
    int v = idx >> 6, j = idx & 63;
    int b = j >> 5, f = j & 31;
    z0[idx] = x[((size_t)b * V + v) * 32 + f];
}

// GroupNorm stage 1: 256 blocks, each reduces 192 rows (both batches) into per-(b,g) partials
__global__ __launch_bounds__(256) void gn_reduce(const float* __restrict__ acc, float* __restrict__ part) {
    int blk = blockIdx.x;
    int tid = threadIdx.x;
    int c = tid & 63;          // channel == lane
    int sub = tid >> 6;        // wave id: row subset
    int v0 = blk * 192;
    float s0 = 0.f, q0 = 0.f, s1 = 0.f, q1 = 0.f;
    for (int i = 0; i < 48; ++i) {
        int v = v0 + sub + (i << 2);
        float a = acc[(size_t)v * 64 + c];
        float b = acc[((size_t)V + v) * 64 + c];
        s0 += a; q0 += a * a; s1 += b; q1 += b * b;
    }
    #pragma unroll
    for (int off = 1; off < 8; off <<= 1) {
        s0 += __shfl_xor(s0, off); q0 += __shfl_xor(q0, off);
        s1 += __shfl_xor(s1, off); q1 += __shfl_xor(q1, off);
    }
    __shared__ float lds[4][8][4];
    int g = c >> 3;
    if ((c & 7) == 0) { lds[sub][g][0] = s0; lds[sub][g][1] = q0; lds[sub][g][2] = s1; lds[sub][g][3] = q1; }
    __syncthreads();
    if (tid < 32) {
        int g2 = tid >> 2, j = tid & 3;
        float r = lds[0][g2][j] + lds[1][g2][j] + lds[2][g2][j] + lds[3][g2][j];
        int b = j >> 1, st = j & 1;
        part[blk * 32 + ((b << 3) + g2) * 2 + st] = r;
    }
}

__global__ __launch_bounds__(256) void gn_finalize(const float* __restrict__ part, float* __restrict__ stats) {
    int t = threadIdx.x;
    int bg = t >> 4, s = t & 15;
    float sum = 0.f, ss = 0.f;
    for (int blk = s; blk < 256; blk += 16) {
        sum += part[blk * 32 + bg * 2];
        ss  += part[blk * 32 + bg * 2 + 1];
    }
    #pragma unroll
    for (int off = 8; off > 0; off >>= 1) { sum += __shfl_down(sum, off, 16); ss += __shfl_down(ss, off, 16); }
    if (s == 0) {
        const float N = (float)V * 8.f;
        float mean = sum / N;
        float var = ss / N - mean * mean;
        stats[bg * 2] = mean;
        stats[bg * 2 + 1] = rsqrtf(var + EPSV);
    }
}

// apply GN + LeakyReLU, writing z-layout [V,128] for conv2
__global__ __launch_bounds__(256) void gn_apply(const float* __restrict__ acc, const float* __restrict__ stats,
                                                const float* __restrict__ gamma, const float* __restrict__ beta,
                                                float* __restrict__ zout) {
    int idx = blockIdx.x * 256 + threadIdx.x;  // < V*128
    int v = idx >> 7, j = idx & 127;
    int b = j >> 6, c = j & 63;
    int bg = (b << 3) + (c >> 3);
    float mean = stats[bg * 2], rstd = stats[bg * 2 + 1];
    float val = acc[((size_t)b * V + v) * 64 + c];
    float y = (val - mean) * rstd * gamma[c] + beta[c];
    zout[idx] = y > 0.f ? y : SLOPE * y;
}

// out already holds the res-conv accumulator; add GN2(conv2)+LeakyReLU in place
__global__ __launch_bounds__(256) void final_out(const float* __restrict__ acc, float* outres,
                                                 const float* __restrict__ stats,
                                                 const float* __restrict__ gamma, const float* __restrict__ beta) {
    int idx = blockIdx.x * 256 + threadIdx.x;  // < B*V*64
    int c = idx & 63;
    int b = idx >= V * 64 ? 1 : 0;
    int bg = (b << 3) + (c >> 3);
    float mean = stats[bg * 2], rstd = stats[bg * 2 + 1];
    float y = (acc[idx] - mean) * rstd * gamma[c] + beta[c];
    y = y > 0.f ? y : SLOPE * y;
    outres[idx] = y + outres[idx];   // read-before-write, same thread/address
}

extern "C" void kernel_launch(void* const* d_in, const int* in_sizes, int n_in,
                              void* d_out, int out_size, void* d_ws, size_t ws_size,
                              hipStream_t stream) {
    const float* x    = (const float*)d_in[0];
    const float* vals = (const float*)d_in[1];
    const int*   col  = (const int*)d_in[3];
    const float* W1   = (const float*)d_in[4];
    const float* b1   = (const float*)d_in[5];
    const float* g1   = (const float*)d_in[6];
    const float* be1  = (const float*)d_in[7];
    const float* W2   = (const float*)d_in[8];
    const float* b2   = (const float*)d_in[9];
    const float* g2   = (const float*)d_in[10];
    const float* be2  = (const float*)d_in[11];
    const float* Wr   = (const float*)d_in[12];
    const float* br   = (const float*)d_in[13];
    float* out = (float*)d_out;   // doubles as the residual-conv accumulator

    // workspace (fp32, ~75.6 MB total):
    //   ACC [2,V,64] 25.2MB | ZA [V,128] 25.2MB | ZB [V,128] 25.2MB | PART 32KB | ST1/ST2
    float* ACC  = (float*)d_ws;
    float* ZA   = ACC + (size_t)2 * V * 64;
    float* ZB   = ZA + (size_t)V * 128;
    float* PART = ZB + (size_t)V * 128;
    float* ST1  = PART + 8192;
    float* ST2  = ST1 + 32;

    const int GB = V / 4;      // cheb_step grid (4 rows per block, 1 per wave)

    reorder_k<<<V * 64 / 256, 256, 0, stream>>>(x, ZA);

    // ---- conv1 + res_conv (dual accumulation over the shared Chebyshev basis of x) ----
    cheb_step<64, 32, true, true><<<GB, 256, 0, stream>>>(
        ZA, ZA, ZB, vals, col, W1, b1, Wr, br, ACC, out, 0.f, 0.f);
    cheb_step<64, 32, true, false><<<GB, 256, 0, stream>>>(
        ZA, ZA, ZB, vals, col, W1 + 1 * 2048, b1, Wr + 1 * 2048, br, ACC, out, 1.f, 0.f);
    {
        float *cur = ZB, *prev = ZA;   // cur = T_{k-1}, prev = T_{k-2}
        for (int k = 2; k < 8; ++k) {
            cheb_step<64, 32, true, false><<<GB, 256, 0, stream>>>(
                cur, prev, prev, vals, col, W1 + k * 2048, b1, Wr + k * 2048, br, ACC, out, 2.f, -1.f);
            float* t = cur; cur = prev; prev = t;
        }
    }

    gn_reduce<<<256, 256, 0, stream>>>(ACC, PART);
    gn_finalize<<<1, 256, 0, stream>>>(PART, ST1);
    gn_apply<<<V * 128 / 256, 256, 0, stream>>>(ACC, ST1, g1, be1, ZA);

    // ---- conv2 on h1 (z-layout [V,128] in ZA) ----
    cheb_step<128, 64, false, true><<<GB, 256, 0, stream>>>(
        ZA, ZA, ZB, vals, col, W2, b2, nullptr, nullptr, ACC, nullptr, 0.f, 0.f);
    cheb_step<128, 64, false, false><<<GB, 256, 0, stream>>>(
        ZA, ZA, ZB, vals, col, W2 + 1 * 4096, b2, nullptr, nullptr, ACC, nullptr, 1.f, 0.f);
    {
        float *cur = ZB, *prev = ZA;
        for (int k = 2; k < 8; ++k) {
            cheb_step<128, 64, false, false><<<GB, 256, 0, stream>>>(
                cur, prev, prev, vals, col, W2 + k * 4096, b2, nullptr, nullptr, ACC, nullptr, 2.f, -1.f);
            float* t = cur; cur = prev; prev = t;
        }
    }

    gn_reduce<<<256, 256, 0, stream>>>(ACC, PART);
    gn_finalize<<<1, 256, 0, stream>>>(PART, ST2);
    final_out<<<2 * V * 64 / 256, 256, 0, stream>>>(ACC, out, ST2, g2, be2);
}

// Round 5
// 445.541 us; speedup vs baseline: 1.7562x; 1.7562x over previous
//
#include <hip/hip_runtime.h>
#include <hip/hip_bf16.h>

#define V 49152
#define NNZ 9
#define EPSV 1e-5f
#define SLOPE 0.1f

typedef __attribute__((ext_vector_type(8))) short bf16x8;   // 8 bf16 (4 VGPRs)
typedef __attribute__((ext_vector_type(4))) float f32x4;    // MFMA C/D

__device__ __forceinline__ float lo2f(unsigned u) { return __uint_as_float(u << 16); }
__device__ __forceinline__ float hi2f(unsigned u) { return __uint_as_float(u & 0xffff0000u); }
__device__ __forceinline__ unsigned short f2us(float f) {
    __hip_bfloat16 h = __float2bfloat16(f);
    return *(unsigned short*)&h;
}
__device__ __forceinline__ float us2f(unsigned short u) { return __uint_as_float(((unsigned)u) << 16); }
__device__ __forceinline__ unsigned pk2(float a, float b) {
    return ((unsigned)f2us(a)) | (((unsigned)f2us(b)) << 16);
}

// ---- prep: convert+transpose weights to bf16 [kk][o][f]; zero GN partial buffers ----
__global__ __launch_bounds__(256) void prep_k(
    const float* __restrict__ W1, const float* __restrict__ Wr, const float* __restrict__ W2,
    unsigned short* __restrict__ Wt1, unsigned short* __restrict__ Wtr, unsigned short* __restrict__ Wt2,
    float* __restrict__ part)   // part: PART1(256) + PART2(256) + slack
{
    int i = blockIdx.x * 256 + threadIdx.x;
    if (i < 32768) {                 // Wt2[kk][o][f] = W2[kk][f][o], F=64
        int kk = i >> 12, rem = i & 4095, o = rem >> 6, f = rem & 63;
        Wt2[i] = f2us(W2[kk * 4096 + f * 64 + o]);
    } else if (i < 49152) {          // Wt1, F=32
        int j = i - 32768;
        int kk = j >> 11, rem = j & 2047, o = rem >> 5, f = rem & 31;
        Wt1[j] = f2us(W1[kk * 2048 + f * 64 + o]);
    } else if (i < 65536) {          // Wtr, F=32
        int j = i - 49152;
        int kk = j >> 11, rem = j & 2047, o = rem >> 5, f = rem & 31;
        Wtr[j] = f2us(Wr[kk * 2048 + f * 64 + o]);
    } else if (i < 66560) {          // zero 1024 floats of partials
        part[i - 65536] = 0.f;
    }
}

// ---- reorder x [B,V,32] f32 -> T0 conv1 layout [V][b*32+f] bf16 (packed dwords) ----
__global__ __launch_bounds__(256) void reorder_k(const float* __restrict__ x, unsigned* __restrict__ t0) {
    int idx = blockIdx.x * 256 + threadIdx.x;   // < V*32 dwords
    int v = idx >> 5, j2 = idx & 31;
    int b = j2 >> 4, f0 = (j2 & 15) * 2;
    const float* p = x + ((size_t)b * V + v) * 32 + f0;
    t0[idx] = pk2(p[0], p[1]);
}

// ---- SpMM-only Chebyshev step: zn = c*(L @ zc) - zp  (bf16 rows, dword-packed) ----
// D: row width in elements (64 conv1 / 128 conv2). FIRST: T1 = L@T0 (no zp term).
template<int D, bool FIRST>
__global__ __launch_bounds__(256) void spmm_step(
    const unsigned* __restrict__ zc, const unsigned* __restrict__ zp, unsigned* __restrict__ zn,
    const float* __restrict__ vals, const int* __restrict__ col)
{
    constexpr int L = D / 2;                      // dwords per row
    int tid = blockIdx.x * 256 + threadIdx.x;     // over V*L
    int v = tid / L;
    int c = tid % L;
    int base = v * NNZ;
    float t0 = 0.f, t1 = 0.f;
    #pragma unroll
    for (int n = 0; n < NNZ; ++n) {
        float a = vals[base + n];
        int cc = col[base + n];
        unsigned u = zc[(size_t)cc * L + c];
        t0 += a * lo2f(u);
        t1 += a * hi2f(u);
    }
    float r0, r1;
    if (FIRST) { r0 = t0; r1 = t1; }
    else {
        unsigned p = zp[(size_t)v * L + c];
        r0 = 2.f * t0 - lo2f(p);
        r1 = 2.f * t1 - hi2f(p);
    }
    zn[(size_t)v * L + c] = pk2(r0, r1);
}

// ---- MFMA GEMM over materialized T_k: ACC[b][v][o] (+ res out) + fused GN partials ----
// T: [NKK][V][2F] bf16 contiguous. WtA/WtB: [NKK][64][F] bf16. F in {32,64}.
// INIT: overwrite ACC (raw partial). FINAL: add bias, RMW ACC if !INIT, emit GN partials.
template<int F, int NKK, bool DUAL, bool INIT, bool FINAL>
__global__ __launch_bounds__(256) void mfma_gemm(
    const unsigned short* __restrict__ T,
    const unsigned short* __restrict__ WtA, const unsigned short* __restrict__ WtB,
    const float* __restrict__ biasA, const float* __restrict__ biasB,
    unsigned short* __restrict__ ACC, float* __restrict__ resOut,
    float* __restrict__ part)
{
    int wv = threadIdx.x >> 6, lane = threadIdx.x & 63;
    int quad = lane >> 4, l15 = lane & 15;
    int v0 = blockIdx.x * 64 + wv * 16;

    __shared__ float sS[2][64], sQ[2][64];
    if (FINAL) {
        if (threadIdx.x < 128) {
            sS[threadIdx.x >> 6][threadIdx.x & 63] = 0.f;
            sQ[threadIdx.x >> 6][threadIdx.x & 63] = 0.f;
        }
        __syncthreads();
    }

    f32x4 acc[2][4];
    f32x4 accd[2][4];
    #pragma unroll
    for (int b = 0; b < 2; ++b)
        #pragma unroll
        for (int ot = 0; ot < 4; ++ot) {
            acc[b][ot] = (f32x4){0.f, 0.f, 0.f, 0.f};
            if (DUAL) accd[b][ot] = (f32x4){0.f, 0.f, 0.f, 0.f};
        }

    #pragma unroll
    for (int kk = 0; kk < NKK; ++kk) {
        #pragma unroll
        for (int fh = 0; fh < F / 32; ++fh) {
            // A-fragments: A[m=l15][k=quad*8+j], one per batch
            size_t arow = (size_t)kk * V * 2 * F + (size_t)(v0 + l15) * 2 * F + fh * 32 + quad * 8;
            bf16x8 a0 = *(const bf16x8*)(const void*)(T + arow);
            bf16x8 a1 = *(const bf16x8*)(const void*)(T + arow + F);
            #pragma unroll
            for (int ot = 0; ot < 4; ++ot) {
                // B-fragment: B[k=quad*8+j][n=l15] from Wt[kk][o][f] (f contiguous)
                size_t brow = ((size_t)kk * 64 + ot * 16 + l15) * F + fh * 32 + quad * 8;
                bf16x8 bw = *(const bf16x8*)(const void*)(WtA + brow);
                acc[0][ot] = __builtin_amdgcn_mfma_f32_16x16x32_bf16(a0, bw, acc[0][ot], 0, 0, 0);
                acc[1][ot] = __builtin_amdgcn_mfma_f32_16x16x32_bf16(a1, bw, acc[1][ot], 0, 0, 0);
                if (DUAL) {
                    bf16x8 bd = *(const bf16x8*)(const void*)(WtB + brow);
                    accd[0][ot] = __builtin_amdgcn_mfma_f32_16x16x32_bf16(a0, bd, accd[0][ot], 0, 0, 0);
                    accd[1][ot] = __builtin_amdgcn_mfma_f32_16x16x32_bf16(a1, bd, accd[1][ot], 0, 0, 0);
                }
            }
        }
    }

    // epilogue: C/D layout col=l15, row=quad*4+reg
    #pragma unroll
    for (int b = 0; b < 2; ++b) {
        #pragma unroll
        for (int ot = 0; ot < 4; ++ot) {
            int o = ot * 16 + l15;
            float bia = FINAL ? biasA[o] : 0.f;
            float s = 0.f, q = 0.f;
            #pragma unroll
            for (int r = 0; r < 4; ++r) {
                int v = v0 + quad * 4 + r;
                size_t idx = ((size_t)b * V + v) * 64 + o;
                float val = acc[b][ot][r] + bia;
                if (!INIT) val += us2f(ACC[idx]);
                ACC[idx] = f2us(val);
                if (FINAL) { s += val; q += val * val; }
                if (DUAL) resOut[idx] = accd[b][ot][r] + biasB[o];
            }
            if (FINAL) {
                s += __shfl_xor(s, 16); s += __shfl_xor(s, 32);
                q += __shfl_xor(q, 16); q += __shfl_xor(q, 32);
                if (quad == 0) {
                    atomicAdd(&sS[b][o], s);
                    atomicAdd(&sQ[b][o], q);
                }
            }
        }
    }
    if (FINAL) {
        __syncthreads();
        if (threadIdx.x < 128) {
            int b = threadIdx.x >> 6, o = threadIdx.x & 63;
            atomicAdd(&part[(b * 64 + o) * 2], sS[b][o]);
            atomicAdd(&part[(b * 64 + o) * 2 + 1], sQ[b][o]);
        }
    }
}

// ---- GN finalize: per-channel partials [2][64][2] -> per-(b,g) stats [16][2] ----
__global__ __launch_bounds__(64) void gn_finalize(const float* __restrict__ part, float* __restrict__ stats) {
    int t = threadIdx.x;
    if (t < 16) {
        int b = t >> 3, g = t & 7;
        float s = 0.f, q = 0.f;
        for (int c = g * 8; c < g * 8 + 8; ++c) {
            s += part[(b * 64 + c) * 2];
            q += part[(b * 64 + c) * 2 + 1];
        }
        const float N = (float)V * 8.f;
        float mean = s / N;
        float var = q / N - mean * mean;
        stats[t * 2] = mean;
        stats[t * 2 + 1] = rsqrtf(var + EPSV);
    }
}

// ---- GN1 + LeakyReLU: ACC bf16 -> conv2 T0 [V][b*64+o] bf16 packed ----
__global__ __launch_bounds__(256) void gn_apply(const unsigned short* __restrict__ ACC,
                                                const float* __restrict__ stats,
                                                const float* __restrict__ gamma, const float* __restrict__ beta,
                                                unsigned* __restrict__ zout) {
    int idx = blockIdx.x * 256 + threadIdx.x;   // < V*64 dwords of [V][128]
    int v = idx >> 6, j2 = idx & 63;
    int b = j2 >> 5, o0 = (j2 & 31) * 2;
    float y[2];
    #pragma unroll
    for (int i = 0; i < 2; ++i) {
        int o = o0 + i;
        int bg = b * 8 + (o >> 3);
        float mean = stats[bg * 2], rstd = stats[bg * 2 + 1];
        float val = us2f(ACC[((size_t)b * V + v) * 64 + o]);
        float t = (val - mean) * rstd * gamma[o] + beta[o];
        y[i] = t > 0.f ? t : SLOPE * t;
    }
    zout[idx] = pk2(y[0], y[1]);
}

// ---- final: out[b][v][o] (holds res) += LeakyReLU(GN2(ACC)) ----
__global__ __launch_bounds__(256) void final_out(const unsigned short* __restrict__ ACC,
                                                 float* outres,
                                                 const float* __restrict__ stats,
                                                 const float* __restrict__ gamma, const float* __restrict__ beta) {
    int idx = blockIdx.x * 256 + threadIdx.x;   // < 2*V*64
    int o = idx & 63;
    int b = idx >= V * 64 ? 1 : 0;
    int bg = b * 8 + (o >> 3);
    float mean = stats[bg * 2], rstd = stats[bg * 2 + 1];
    float y = (us2f(ACC[idx]) - mean) * rstd * gamma[o] + beta[o];
    y = y > 0.f ? y : SLOPE * y;
    outres[idx] = y + outres[idx];
}

extern "C" void kernel_launch(void* const* d_in, const int* in_sizes, int n_in,
                              void* d_out, int out_size, void* d_ws, size_t ws_size,
                              hipStream_t stream) {
    const float* x    = (const float*)d_in[0];
    const float* vals = (const float*)d_in[1];
    const int*   col  = (const int*)d_in[3];
    const float* W1   = (const float*)d_in[4];
    const float* b1   = (const float*)d_in[5];
    const float* g1   = (const float*)d_in[6];
    const float* be1  = (const float*)d_in[7];
    const float* W2   = (const float*)d_in[8];
    const float* b2   = (const float*)d_in[9];
    const float* g2   = (const float*)d_in[10];
    const float* be2  = (const float*)d_in[11];
    const float* Wr   = (const float*)d_in[12];
    const float* br   = (const float*)d_in[13];
    float* out = (float*)d_out;   // res accumulator, then final output

    // workspace (~63.1 MB):
    //   TS   bf16  4*[V][128]  50.33MB  (conv1 uses it as 8*[V][64])
    //   ACC  bf16  [2][V][64]  12.58MB
    //   Wt1/Wtr [8][64][32], Wt2 [8][64][64] bf16: 128KB
    //   PART1[256] PART2[256] ST1[32] ST2[32] f32
    unsigned short* TS  = (unsigned short*)d_ws;
    unsigned short* ACC = TS + (size_t)4 * V * 128;
    unsigned short* Wt1 = ACC + (size_t)2 * V * 64;
    unsigned short* Wtr = Wt1 + 8 * 64 * 32;
    unsigned short* Wt2 = Wtr + 8 * 64 * 32;
    float* PART1 = (float*)(Wt2 + 8 * 64 * 64);
    float* PART2 = PART1 + 256;
    float* ST1   = PART2 + 256;
    float* ST2   = ST1 + 32;

    prep_k<<<260, 256, 0, stream>>>(W1, Wr, W2, Wt1, Wtr, Wt2, PART1);

    // ---- conv1 basis: T0..T7 in 8 slots of [V][64] bf16 ----
    unsigned* T1s[8];
    for (int k = 0; k < 8; ++k) T1s[k] = (unsigned*)(TS + (size_t)k * V * 64);

    reorder_k<<<V * 32 / 256, 256, 0, stream>>>(x, T1s[0]);
    spmm_step<64, true><<<V * 32 / 256, 256, 0, stream>>>(T1s[0], nullptr, T1s[1], vals, col);
    for (int k = 2; k < 8; ++k)
        spmm_step<64, false><<<V * 32 / 256, 256, 0, stream>>>(T1s[k-1], T1s[k-2], T1s[k], vals, col);

    // conv1 + res: one MFMA pass over all 8 T_k
    mfma_gemm<32, 8, true, true, true><<<V / 64, 256, 0, stream>>>(
        TS, Wt1, Wtr, b1, br, ACC, out, PART1);
    gn_finalize<<<1, 64, 0, stream>>>(PART1, ST1);

    // ---- conv2: GN1-applied h1 as T0 in slot0 of [V][128] ----
    unsigned* T2s[4];
    for (int k = 0; k < 4; ++k) T2s[k] = (unsigned*)(TS + (size_t)k * V * 128);

    gn_apply<<<V * 64 / 256, 256, 0, stream>>>(ACC, ST1, g1, be1, T2s[0]);
    spmm_step<128, true><<<V * 64 / 256, 256, 0, stream>>>(T2s[0], nullptr, T2s[1], vals, col);
    spmm_step<128, false><<<V * 64 / 256, 256, 0, stream>>>(T2s[1], T2s[0], T2s[2], vals, col);
    spmm_step<128, false><<<V * 64 / 256, 256, 0, stream>>>(T2s[2], T2s[1], T2s[3], vals, col);

    // GEMM pass a: kk 0..3 (INIT)
    mfma_gemm<64, 4, false, true, false><<<V / 64, 256, 0, stream>>>(
        TS, Wt2, nullptr, b2, nullptr, ACC, nullptr, PART2);

    // steps 4..7 reuse slots 0..3 (T4->s0, T5->s1, T6->s2, T7->s3)
    spmm_step<128, false><<<V * 64 / 256, 256, 0, stream>>>(T2s[3], T2s[2], T2s[0], vals, col);
    spmm_step<128, false><<<V * 64 / 256, 256, 0, stream>>>(T2s[0], T2s[3], T2s[1], vals, col);
    spmm_step<128, false><<<V * 64 / 256, 256, 0, stream>>>(T2s[1], T2s[0], T2s[2], vals, col);
    spmm_step<128, false><<<V * 64 / 256, 256, 0, stream>>>(T2s[2], T2s[1], T2s[3], vals, col);

    // GEMM pass b: kk 4..7 (RMW + bias + GN2 partials)
    mfma_gemm<64, 4, false, false, true><<<V / 64, 256, 0, stream>>>(
        TS, Wt2 + 4 * 64 * 64, nullptr, b2, nullptr, ACC, nullptr, PART2);
    gn_finalize<<<1, 64, 0, stream>>>(PART2, ST2);

    final_out<<<2 * V * 64 / 256, 256, 0, stream>>>(ACC, out, ST2, g2, be2);
}

// Round 6
// 444.257 us; speedup vs baseline: 1.7612x; 1.0029x over previous
//
#include <hip/hip_runtime.h>
#include <hip/hip_bf16.h>

#define V 49152
#define NNZ 9
#define EPSV 1e-5f
#define SLOPE 0.1f

typedef __attribute__((ext_vector_type(8))) short bf16x8;   // 8 bf16 (4 VGPRs)
typedef __attribute__((ext_vector_type(4))) float f32x4;    // MFMA C/D

__device__ __forceinline__ float lo2f(unsigned u) { return __uint_as_float(u << 16); }
__device__ __forceinline__ float hi2f(unsigned u) { return __uint_as_float(u & 0xffff0000u); }
__device__ __forceinline__ unsigned short f2us(float f) {
    __hip_bfloat16 h = __float2bfloat16(f);
    return *(unsigned short*)&h;
}
__device__ __forceinline__ float us2f(unsigned short u) { return __uint_as_float(((unsigned)u) << 16); }
__device__ __forceinline__ unsigned pk2(float a, float b) {
    return ((unsigned)f2us(a)) | (((unsigned)f2us(b)) << 16);
}

// async 16B/lane global->LDS; lds base must be wave-uniform (lane*16 auto-offset)
__device__ __forceinline__ void gload_lds16(const void* g, void* l) {
    __builtin_amdgcn_global_load_lds((__attribute__((address_space(1))) void*)g,
                                     (__attribute__((address_space(3))) void*)l, 16, 0, 0);
}

// ---- prep: convert+transpose weights to bf16 [kk][o][f]; zero GN partial buffers ----
__global__ __launch_bounds__(256) void prep_k(
    const float* __restrict__ W1, const float* __restrict__ Wr, const float* __restrict__ W2,
    unsigned short* __restrict__ Wt1, unsigned short* __restrict__ Wtr, unsigned short* __restrict__ Wt2,
    float* __restrict__ part)
{
    int i = blockIdx.x * 256 + threadIdx.x;
    if (i < 32768) {                 // Wt2[kk][o][f] = W2[kk][f][o], F=64
        int kk = i >> 12, rem = i & 4095, o = rem >> 6, f = rem & 63;
        Wt2[i] = f2us(W2[kk * 4096 + f * 64 + o]);
    } else if (i < 49152) {          // Wt1, F=32
        int j = i - 32768;
        int kk = j >> 11, rem = j & 2047, o = rem >> 5, f = rem & 31;
        Wt1[j] = f2us(W1[kk * 2048 + f * 64 + o]);
    } else if (i < 65536) {          // Wtr, F=32
        int j = i - 49152;
        int kk = j >> 11, rem = j & 2047, o = rem >> 5, f = rem & 31;
        Wtr[j] = f2us(Wr[kk * 2048 + f * 64 + o]);
    } else if (i < 66560) {
        part[i - 65536] = 0.f;
    }
}

// ---- reorder x [B,V,32] f32 -> T0 conv1 layout [V][b*32+f] bf16 (packed dwords) ----
__global__ __launch_bounds__(256) void reorder_k(const float* __restrict__ x, unsigned* __restrict__ t0) {
    int idx = blockIdx.x * 256 + threadIdx.x;   // < V*32 dwords
    int v = idx >> 5, j2 = idx & 31;
    int b = j2 >> 4, f0 = (j2 & 15) * 2;
    const float* p = x + ((size_t)b * V + v) * 32 + f0;
    t0[idx] = pk2(p[0], p[1]);
}

// ---- SpMM Chebyshev step, uint4-vectorized: zn = 2*(L@zc) - zp (bf16 rows) ----
// L4 = uint4 per row (conv1: 8, conv2: 16). FIRST: zn = L@zc.
template<int L4, bool FIRST>
__global__ __launch_bounds__(256) void spmm_step(
    const uint4* __restrict__ zc, const uint4* __restrict__ zp, uint4* __restrict__ zn,
    const float* __restrict__ vals, const int* __restrict__ col)
{
    int tid = blockIdx.x * 256 + threadIdx.x;     // over V*L4
    int v = tid / L4;
    int c = tid - v * L4;
    int base = v * NNZ;
    float t[8] = {0.f,0.f,0.f,0.f,0.f,0.f,0.f,0.f};
    #pragma unroll
    for (int n = 0; n < NNZ; ++n) {
        float a = vals[base + n];
        int cc = col[base + n];
        uint4 u = zc[(size_t)cc * L4 + c];
        t[0] += a * lo2f(u.x); t[1] += a * hi2f(u.x);
        t[2] += a * lo2f(u.y); t[3] += a * hi2f(u.y);
        t[4] += a * lo2f(u.z); t[5] += a * hi2f(u.z);
        t[6] += a * lo2f(u.w); t[7] += a * hi2f(u.w);
    }
    if (!FIRST) {
        uint4 p = zp[(size_t)v * L4 + c];
        t[0] = 2.f*t[0] - lo2f(p.x); t[1] = 2.f*t[1] - hi2f(p.x);
        t[2] = 2.f*t[2] - lo2f(p.y); t[3] = 2.f*t[3] - hi2f(p.y);
        t[4] = 2.f*t[4] - lo2f(p.z); t[5] = 2.f*t[5] - hi2f(p.z);
        t[6] = 2.f*t[6] - lo2f(p.w); t[7] = 2.f*t[7] - hi2f(p.w);
    }
    uint4 r;
    r.x = pk2(t[0], t[1]); r.y = pk2(t[2], t[3]);
    r.z = pk2(t[4], t[5]); r.w = pk2(t[6], t[7]);
    zn[(size_t)v * L4 + c] = r;
}

// ---- MFMA GEMM over materialized T_k, LDS-staged A (global_load_lds + XOR swizzle) ----
// T: [NKK][V][2F] bf16. WtA/WtB: [NKK][64][F] bf16. F in {32,64}; NKK*2F == 512 (64KB tile).
template<int F, int NKK, bool DUAL, bool INIT, bool FINAL>
__global__ __launch_bounds__(256) void mfma_gemm(
    const unsigned short* __restrict__ T,
    const unsigned short* __restrict__ WtA, const unsigned short* __restrict__ WtB,
    const float* __restrict__ biasA, const float* __restrict__ biasB,
    unsigned short* __restrict__ ACC, float* __restrict__ resOut,
    float* __restrict__ part)
{
    constexpr int CPR = F / 4;                 // 16B chunks per row (2F elems * 2B / 16B)
    __shared__ unsigned short tile[NKK * 64 * 2 * F];   // exactly 64 KB

    int wv = threadIdx.x >> 6, lane = threadIdx.x & 63;
    int quad = lane >> 4, l15 = lane & 15;
    int v0 = blockIdx.x * 64;

    // stage: LDS slot s holds global chunk (s&~7)|((s&7)^(row&7)) of its row
    #pragma unroll
    for (int i = 0; i < 16; ++i) {
        int s = (i * 4 + wv) * 64 + lane;       // slot id 0..4095 (16B units)
        int kk = s / (64 * CPR);
        int ws = s - kk * 64 * CPR;
        int row = ws / CPR;
        int cl = ws - row * CPR;
        int cg = (cl & ~7) | ((cl & 7) ^ (row & 7));
        const unsigned short* gp = T + ((size_t)kk * V + v0 + row) * (2 * F) + cg * 8;
        gload_lds16(gp, tile + (size_t)(i * 4 + wv) * 64 * 8);
    }
    __syncthreads();

    f32x4 acc[2][4];
    f32x4 accd[2][4];
    #pragma unroll
    for (int b = 0; b < 2; ++b)
        #pragma unroll
        for (int ot = 0; ot < 4; ++ot) {
            acc[b][ot] = (f32x4){0.f, 0.f, 0.f, 0.f};
            if (DUAL) accd[b][ot] = (f32x4){0.f, 0.f, 0.f, 0.f};
        }

    int r = wv * 16 + l15;          // tile-local row of this lane's A fragment
    int rx = r & 7;

    #pragma unroll
    for (int kk = 0; kk < NKK; ++kk) {
        #pragma unroll
        for (int fh = 0; fh < F / 32; ++fh) {
            int c0 = fh * 4 + quad;             // batch0 chunk
            int c1 = (CPR / 2) + fh * 4 + quad; // batch1 chunk
            int s0 = (c0 & ~7) | ((c0 & 7) ^ rx);
            int s1 = (c1 & ~7) | ((c1 & 7) ^ rx);
            const unsigned short* rbase = tile + ((size_t)kk * 64 + r) * 2 * F;
            bf16x8 a0 = *(const bf16x8*)(const void*)(rbase + s0 * 8);
            bf16x8 a1 = *(const bf16x8*)(const void*)(rbase + s1 * 8);
            #pragma unroll
            for (int ot = 0; ot < 4; ++ot) {
                size_t brow = ((size_t)kk * 64 + ot * 16 + l15) * F + fh * 32 + quad * 8;
                bf16x8 bw = *(const bf16x8*)(const void*)(WtA + brow);
                acc[0][ot] = __builtin_amdgcn_mfma_f32_16x16x32_bf16(a0, bw, acc[0][ot], 0, 0, 0);
                acc[1][ot] = __builtin_amdgcn_mfma_f32_16x16x32_bf16(a1, bw, acc[1][ot], 0, 0, 0);
                if (DUAL) {
                    bf16x8 bd = *(const bf16x8*)(const void*)(WtB + brow);
                    accd[0][ot] = __builtin_amdgcn_mfma_f32_16x16x32_bf16(a0, bd, accd[0][ot], 0, 0, 0);
                    accd[1][ot] = __builtin_amdgcn_mfma_f32_16x16x32_bf16(a1, bd, accd[1][ot], 0, 0, 0);
                }
            }
        }
    }

    // GN partial scratch reuses the (now consumed) tile
    float* sS = (float*)tile;        // [2][64]
    float* sQ = sS + 128;            // [2][64]
    if (FINAL) {
        __syncthreads();
        if (threadIdx.x < 128) { sS[threadIdx.x] = 0.f; sQ[threadIdx.x] = 0.f; }
        __syncthreads();
    }

    // epilogue: C/D layout col=l15, row=quad*4+reg
    #pragma unroll
    for (int b = 0; b < 2; ++b) {
        #pragma unroll
        for (int ot = 0; ot < 4; ++ot) {
            int o = ot * 16 + l15;
            float bia = FINAL ? biasA[o] : 0.f;
            float s = 0.f, q = 0.f;
            #pragma unroll
            for (int rr = 0; rr < 4; ++rr) {
                int v = v0 + wv * 16 + quad * 4 + rr;
                size_t idx = ((size_t)b * V + v) * 64 + o;
                float val = acc[b][ot][rr] + bia;
                if (!INIT) val += us2f(ACC[idx]);
                ACC[idx] = f2us(val);
                if (FINAL) { s += val; q += val * val; }
                if (DUAL) resOut[idx] = accd[b][ot][rr] + biasB[o];
            }
            if (FINAL) {
                s += __shfl_xor(s, 16); s += __shfl_xor(s, 32);
                q += __shfl_xor(q, 16); q += __shfl_xor(q, 32);
                if (quad == 0) {
                    atomicAdd(&sS[b * 64 + o], s);
                    atomicAdd(&sQ[b * 64 + o], q);
                }
            }
        }
    }
    if (FINAL) {
        __syncthreads();
        if (threadIdx.x < 128) {
            int b = threadIdx.x >> 6, o = threadIdx.x & 63;
            atomicAdd(&part[(b * 64 + o) * 2], sS[b * 64 + o]);
            atomicAdd(&part[(b * 64 + o) * 2 + 1], sQ[b * 64 + o]);
        }
    }
}

// ---- GN finalize: per-channel partials [2][64][2] -> per-(b,g) stats [16][2] ----
__global__ __launch_bounds__(64) void gn_finalize(const float* __restrict__ part, float* __restrict__ stats) {
    int t = threadIdx.x;
    if (t < 16) {
        int b = t >> 3, g = t & 7;
        float s = 0.f, q = 0.f;
        for (int c = g * 8; c < g * 8 + 8; ++c) {
            s += part[(b * 64 + c) * 2];
            q += part[(b * 64 + c) * 2 + 1];
        }
        const float N = (float)V * 8.f;
        float mean = s / N;
        float var = q / N - mean * mean;
        stats[t * 2] = mean;
        stats[t * 2 + 1] = rsqrtf(var + EPSV);
    }
}

// ---- GN1 + LeakyReLU: ACC bf16 -> conv2 T0 [V][b*64+o] bf16 packed ----
__global__ __launch_bounds__(256) void gn_apply(const unsigned short* __restrict__ ACC,
                                                const float* __restrict__ stats,
                                                const float* __restrict__ gamma, const float* __restrict__ beta,
                                                unsigned* __restrict__ zout) {
    int idx = blockIdx.x * 256 + threadIdx.x;   // < V*64 dwords of [V][128]
    int v = idx >> 6, j2 = idx & 63;
    int b = j2 >> 5, o0 = (j2 & 31) * 2;
    float y[2];
    #pragma unroll
    for (int i = 0; i < 2; ++i) {
        int o = o0 + i;
        int bg = b * 8 + (o >> 3);
        float mean = stats[bg * 2], rstd = stats[bg * 2 + 1];
        float val = us2f(ACC[((size_t)b * V + v) * 64 + o]);
        float t = (val - mean) * rstd * gamma[o] + beta[o];
        y[i] = t > 0.f ? t : SLOPE * t;
    }
    zout[idx] = pk2(y[0], y[1]);
}

// ---- final: out[b][v][o] (holds res) += LeakyReLU(GN2(ACC)) ----
__global__ __launch_bounds__(256) void final_out(const unsigned short* __restrict__ ACC,
                                                 float* outres,
                                                 const float* __restrict__ stats,
                                                 const float* __restrict__ gamma, const float* __restrict__ beta) {
    int idx = blockIdx.x * 256 + threadIdx.x;   // < 2*V*64
    int o = idx & 63;
    int b = idx >= V * 64 ? 1 : 0;
    int bg = b * 8 + (o >> 3);
    float mean = stats[bg * 2], rstd = stats[bg * 2 + 1];
    float y = (us2f(ACC[idx]) - mean) * rstd * gamma[o] + beta[o];
    y = y > 0.f ? y : SLOPE * y;
    outres[idx] = y + outres[idx];
}

extern "C" void kernel_launch(void* const* d_in, const int* in_sizes, int n_in,
                              void* d_out, int out_size, void* d_ws, size_t ws_size,
                              hipStream_t stream) {
    const float* x    = (const float*)d_in[0];
    const float* vals = (const float*)d_in[1];
    const int*   col  = (const int*)d_in[3];
    const float* W1   = (const float*)d_in[4];
    const float* b1   = (const float*)d_in[5];
    const float* g1   = (const float*)d_in[6];
    const float* be1  = (const float*)d_in[7];
    const float* W2   = (const float*)d_in[8];
    const float* b2   = (const float*)d_in[9];
    const float* g2   = (const float*)d_in[10];
    const float* be2  = (const float*)d_in[11];
    const float* Wr   = (const float*)d_in[12];
    const float* br   = (const float*)d_in[13];
    float* out = (float*)d_out;

    // workspace (~63.1 MB): TS bf16 4*[V][128] | ACC bf16 [2][V][64] | Wt1/Wtr/Wt2 | PART/ST
    unsigned short* TS  = (unsigned short*)d_ws;
    unsigned short* ACC = TS + (size_t)4 * V * 128;
    unsigned short* Wt1 = ACC + (size_t)2 * V * 64;
    unsigned short* Wtr = Wt1 + 8 * 64 * 32;
    unsigned short* Wt2 = Wtr + 8 * 64 * 32;
    float* PART1 = (float*)(Wt2 + 8 * 64 * 64);
    float* PART2 = PART1 + 256;
    float* ST1   = PART2 + 256;
    float* ST2   = ST1 + 32;

    prep_k<<<260, 256, 0, stream>>>(W1, Wr, W2, Wt1, Wtr, Wt2, PART1);

    // ---- conv1 basis: T0..T7 in 8 slots of [V][64] bf16 ----
    uint4* T1s[8];
    for (int k = 0; k < 8; ++k) T1s[k] = (uint4*)(TS + (size_t)k * V * 64);

    reorder_k<<<V * 32 / 256, 256, 0, stream>>>(x, (unsigned*)T1s[0]);
    spmm_step<8, true><<<V * 8 / 256, 256, 0, stream>>>(T1s[0], nullptr, T1s[1], vals, col);
    for (int k = 2; k < 8; ++k)
        spmm_step<8, false><<<V * 8 / 256, 256, 0, stream>>>(T1s[k-1], T1s[k-2], T1s[k], vals, col);

    // conv1 + res: one MFMA pass over all 8 T_k
    mfma_gemm<32, 8, true, true, true><<<V / 64, 256, 0, stream>>>(
        TS, Wt1, Wtr, b1, br, ACC, out, PART1);
    gn_finalize<<<1, 64, 0, stream>>>(PART1, ST1);

    // ---- conv2: GN1-applied h1 as T0 in slot0 of [V][128] ----
    uint4* T2s[4];
    for (int k = 0; k < 4; ++k) T2s[k] = (uint4*)(TS + (size_t)k * V * 128);

    gn_apply<<<V * 64 / 256, 256, 0, stream>>>(ACC, ST1, g1, be1, (unsigned*)T2s[0]);
    spmm_step<16, true><<<V * 16 / 256, 256, 0, stream>>>(T2s[0], nullptr, T2s[1], vals, col);
    spmm_step<16, false><<<V * 16 / 256, 256, 0, stream>>>(T2s[1], T2s[0], T2s[2], vals, col);
    spmm_step<16, false><<<V * 16 / 256, 256, 0, stream>>>(T2s[2], T2s[1], T2s[3], vals, col);

    // GEMM pass a: kk 0..3 (INIT)
    mfma_gemm<64, 4, false, true, false><<<V / 64, 256, 0, stream>>>(
        TS, Wt2, nullptr, b2, nullptr, ACC, nullptr, PART2);

    // steps 4..7 reuse slots 0..3
    spmm_step<16, false><<<V * 16 / 256, 256, 0, stream>>>(T2s[3], T2s[2], T2s[0], vals, col);
    spmm_step<16, false><<<V * 16 / 256, 256, 0, stream>>>(T2s[0], T2s[3], T2s[1], vals, col);
    spmm_step<16, false><<<V * 16 / 256, 256, 0, stream>>>(T2s[1], T2s[0], T2s[2], vals, col);
    spmm_step<16, false><<<V * 16 / 256, 256, 0, stream>>>(T2s[2], T2s[1], T2s[3], vals, col);

    // GEMM pass b: kk 4..7 (RMW + bias + GN2 partials)
    mfma_gemm<64, 4, false, false, true><<<V / 64, 256, 0, stream>>>(
        TS, Wt2 + 4 * 64 * 64, nullptr, b2, nullptr, ACC, nullptr, PART2);
    gn_finalize<<<1, 64, 0, stream>>>(PART2, ST2);

    final_out<<<2 * V * 64 / 256, 256, 0, stream>>>(ACC, out, ST2, g2, be2);
}